// Round 16
// baseline (234.144 us; speedup 1.0000x reference)
//
#include <hip/hip_runtime.h>

// LTFGW semi-relaxed FGW — round 16: residency via small blocks + LDS overlay.
// Round-15 falsified the register-squeeze theory: VALU-issue work is constant
//   (~112 us) at VGPR 36 or 52; the waves_per_eu cap only cut occupancy
//   (59->41%) and regressed. REVERTED. The lever is more schedulable blocks:
//   KPB 4->2, BS 512->256, and s_adj (7.6 KB, dead after preamble) overlaid
//   onto s_T (first written inside the loop, after masks live in registers).
//   LDS 36.9 -> 14.9 KB/block -> 8 x 256-thr blocks/CU = 32 waves (100%
//   theoretical) vs ~59% measured at 512-thr blocks. Preamble now runs per
//   k-pair (~+4 us) — paid for by latency hiding on the 3-barrier DS chain.
// gcost v5 (round-14) unchanged. Loop body byte-equal to round 13/14.

#define NN    6000
#define DEG   16
#define MM    17
#define NTPL  16
#define MT    10
#define NF    128
#define NITER 10
#define KPB   2
#define NPB   7
#define BS    256
#define RS    12            // padded T row stride (floats)
#define LOG2E 1.44269504088896340736f

template<int C>
__device__ __forceinline__ float ror_add(float v) {
    int s = __builtin_amdgcn_update_dpp(0, __float_as_int(v), C, 0xf, 0xf, true);
    return v + __int_as_float(s);
}

__device__ __forceinline__ float fexp2(float x) { return __builtin_amdgcn_exp2f(x); }
__device__ __forceinline__ float frcp(float x)  { return __builtin_amdgcn_rcpf(x); }

// sum over each 16-lane row (all lanes get the sum) — pure VALU DPP
__device__ __forceinline__ float reduce16(float v) {
    v = ror_add<0x121>(v);
    v = ror_add<0x122>(v);
    v = ror_add<0x124>(v);
    v = ror_add<0x128>(v);
    return v;
}

// ---------------- gcost v5 (round-14 verbatim)
#define GNV 40
__global__ __launch_bounds__(256) void gcost_kernel(
    const float* __restrict__ x, const float* __restrict__ F2g,
    const float* __restrict__ alpha0, float* __restrict__ G)
{
    const int kt  = blockIdx.y * 16 + (threadIdx.x >> 4);   // grid.y=10 -> 0..159
    const int l16 = threadIdx.x & 15;

    const float4* f2p = reinterpret_cast<const float4*>(F2g + (size_t)kt * NF) + l16 * 2;
    const float4 f2a = f2p[0], f2b = f2p[1];
    float sq = reduce16(f2a.x * f2a.x + f2a.y * f2a.y + f2a.z * f2a.z + f2a.w * f2a.w
                      + f2b.x * f2b.x + f2b.y * f2b.y + f2b.z * f2b.z + f2b.w * f2b.w);

    const float alpha  = 1.f / (1.f + __expf(-alpha0[0]));
    const float mcoefl = (1.f - alpha) * 10.f * LOG2E;
    const float base   = mcoefl * sq;
    const float m2     = -2.f * mcoefl;

    const int v0 = blockIdx.x * GNV;
    #pragma unroll 4
    for (int i = 0; i < GNV; i++) {
        const int v = v0 + i;
        const float4* xp = reinterpret_cast<const float4*>(x + (size_t)v * NF) + l16 * 2;
        float4 xa = xp[0], xb = xp[1];
        float d = xa.x * f2a.x + xa.y * f2a.y + xa.z * f2a.z + xa.w * f2a.w
                + xb.x * f2b.x + xb.y * f2b.y + xb.z * f2b.z + xb.w * f2b.w;
        d = reduce16(d);
        if (l16 == 0)
            G[(size_t)v * (NTPL * MT) + kt] = fmaf(m2, d, base);
    }
}

// ---------------- main kernel
__global__ __launch_bounds__(BS, 8) void srfgw_kernel(
    const float* __restrict__ x,
    const int*   __restrict__ dst,
    const float* __restrict__ C2g,
    const float* __restrict__ F2g,
    const float* __restrict__ alpha0,
    const float* __restrict__ G,
    int useG,
    float*       __restrict__ out)
{
    const int nb  = blockIdx.x * NPB;
    const int kb  = blockIdx.y * KPB;
    const int tid = threadIdx.x;

    __shared__ __align__(16) float s_T[KPB][NPB][MM][RS];     // 11424 B
    __shared__ __align__(16) float s_C2sq[KPB][MT][RS];       // 960 B
    __shared__ __align__(16) float s_q[KPB][NPB][RS];         // 672 B
    __shared__ __align__(16) float s_cc[KPB][NPB][RS];        // 672 B
    __shared__ __align__(16) float s_A[KPB][RS];              // 96 B
    __shared__ __align__(16) float s_B[KPB][RS];              // 96 B
    __shared__ int      s_nbr[NPB][MM];
    __shared__ unsigned s_mask[NPB][MM];
    // s_adj (119*16 ints = 7616 B) OVERLAID on s_T: dead after the mask
    // build; s_T is first written inside the loop, after masks are consumed
    // into registers. 7616 <= 11424 B.
    int* s_adj = reinterpret_cast<int*>(&s_T[0][0][0][0]);

    const float aval  = alpha0[0];
    const float alpha = 1.f / (1.f + __expf(-aval));
    const float gcoef = 2.f * alpha * 10.f;
    const float tgl   = 2.f * gcoef * LOG2E;
    const float gl2   = gcoef * LOG2E;

    // nbr (119 <= BS); node clamp: 7 does not divide 6000
    if (tid < NPB * MM) {
        int node = tid / MM, a0 = tid - node * MM;
        int nd  = nb + node;
        int ndc = nd < NN ? nd : NN - 1;
        s_nbr[node][a0]  = (a0 == 0) ? ndc : dst[(size_t)ndc * DEG + a0 - 1];
        s_mask[node][a0] = 0u;
    }
    __syncthreads();

    // adjacency rows (1904 > BS -> strided; writes the s_T-overlaid region)
    for (int i = tid; i < NPB * MM * DEG; i += BS) {
        int r = i >> 4, j = i & 15;
        int node = r / MM, a0 = r - node * MM;
        s_adj[r * DEG + j] = dst[(size_t)s_nbr[node][a0] * DEG + j];
    }
    // C2sq (200 <= BS but keep strided; kb offset)
    for (int i = tid; i < KPB * MT * MT; i += BS) {
        int kk = i / (MT * MT), rr = i - kk * (MT * MT);
        int rs = rr / MT, rt = rr - rs * MT;
        float v = C2g[(size_t)kb * MT * MT + i];
        s_C2sq[kk][rs][rt] = gl2 * v * v;
    }
    // iter-0 fold constants (20 <= BS)
    if (tid < KPB * MT) {
        int kk = tid / MT, s = tid - kk * MT;
        const float* cr = C2g + (size_t)(kb + kk) * MT * MT + s * MT;
        float rs = 0.f, rq = 0.f;
        #pragma unroll
        for (int t = 0; t < MT; t++) { float c = cr[t]; rs += c; rq = fmaf(c, c, rq); }
        s_A[kk][s] = (tgl / 170.f) * rs;
        s_B[kk][s] = 0.1f * gl2 * rq;
    }
    __syncthreads();

    // masks (2023 > BS -> strided), dual atomicOr symmetrization
    for (int i = tid; i < NPB * MM * MM; i += BS) {
        int node = i / (MM * MM), rr = i - node * (MM * MM);
        int pa = rr / MM, pb = rr - pa * MM;
        int vtgt = s_nbr[node][pb];
        const int* ar = s_adj + (node * MM + pa) * DEG;
        bool e = false;
        #pragma unroll
        for (int j = 0; j < DEG; j++) e = e | (ar[j] == vtgt);
        if (e) {
            atomicOr(&s_mask[node][pa], 1u << pb);
            atomicOr(&s_mask[node][pb], 1u << pa);
        }
    }
    __syncthreads();

    // ---- row mapping: kh wave-uniform (waves 0-1 -> k0, 2-3 -> k1);
    //      119 rows flat-packed in 128 lanes ----
    const int  kh     = tid >> 7;              // 0..1
    const int  L      = tid & 127;
    const bool rvalid = L < NPB * MM;          // 119
    int gR = L / MM;
    int aR = L - gR * MM;
    if (!rvalid) { gR = 0; aR = 0; }

    const int k_u = __builtin_amdgcn_readfirstlane(kb + kh);
    const float* __restrict__ c2p = C2g + (size_t)k_u * MT * MT;

    const int vv = s_nbr[gR][aR];

    float Mc[MT];
    if (useG) {
        const float2* gp = reinterpret_cast<const float2*>(G + (size_t)vv * (NTPL * MT) + k_u * MT);
        #pragma unroll
        for (int j = 0; j < 5; j++) {
            float2 w = gp[j];
            Mc[2 * j] = w.x; Mc[2 * j + 1] = w.y;
        }
    } else {
        float dot[MT], sq2[MT];
        #pragma unroll
        for (int t = 0; t < MT; t++) { dot[t] = 0.f; sq2[t] = 0.f; }
        const float4* xr = reinterpret_cast<const float4*>(x + (size_t)vv * NF);
        const float4* fr = reinterpret_cast<const float4*>(F2g + (size_t)k_u * MT * NF);
        for (int f = 0; f < NF / 4; f++) {
            float4 xa = xr[f];
            #pragma unroll
            for (int t = 0; t < MT; t++) {
                float4 b = fr[t * (NF / 4) + f];
                dot[t] += xa.x * b.x + xa.y * b.y + xa.z * b.z + xa.w * b.w;
                sq2[t] += b.x * b.x + b.y * b.y + b.z * b.z + b.w * b.w;
            }
        }
        const float mcoefl = (1.f - alpha) * 10.f * LOG2E;
        #pragma unroll
        for (int t = 0; t < MT; t++) Mc[t] = mcoefl * (sq2[t] - 2.f * dot[t]);
    }

    unsigned mask = rvalid ? s_mask[gR][aR] : 0u;
    const int  pcnt = __popc(mask);
    const bool cmpl = pcnt > 8;
    unsigned   lmask = cmpl ? (~mask & 0x1FFFFu) : mask;
    if (!rvalid) lmask = 0u;
    const float sgn = cmpl ? -1.f : 1.f;
    const float P   = 1.f / 17.f;

    // ---- iter-0 analytic fold ----
    float lt[MT];
    {
        const float pcf = (float)pcnt;
        const float2* Ap = reinterpret_cast<const float2*>(&s_A[kh][0]);
        const float2* Bp = reinterpret_cast<const float2*>(&s_B[kh][0]);
        #pragma unroll
        for (int j = 0; j < 5; j++) {
            float2 av = Ap[j], bv = Bp[j];
            lt[2 * j]     = fmaf(pcf, av.x, -bv.x - Mc[2 * j]);
            lt[2 * j + 1] = fmaf(pcf, av.y, -bv.y - Mc[2 * j + 1]);
        }
    }

    // ---- colsum/cc mapping: tid < 140 -> (ck, cn, ct) ----
    const bool cvalid = tid < KPB * NPB * MT;  // 140
    int ck = 0, cn = 0, ct = 0;
    if (cvalid) {
        ck = tid / (NPB * MT);
        int rem = tid - ck * (NPB * MT);
        cn = rem / MT;
        ct = rem - cn * MT;
    }
    float qa = 0.f;

    float4* Trow = reinterpret_cast<float4*>(&s_T[kh][gR][aR][0]);

    for (int it = 1; it <= NITER; it++) {
        // thread-local softmax (log2 domain)
        float mx = lt[0];
        #pragma unroll
        for (int t = 1; t < MT; t++) mx = fmaxf(mx, lt[t]);
        float e[MT], ss = 0.f;
        #pragma unroll
        for (int t = 0; t < MT; t++) { e[t] = fexp2(lt[t] - mx); ss += e[t]; }
        float sc = P * frcp(ss);
        #pragma unroll
        for (int t = 0; t < MT; t++) e[t] *= sc;

        if (rvalid) {
            Trow[0] = make_float4(e[0], e[1], e[2], e[3]);
            Trow[1] = make_float4(e[4], e[5], e[6], e[7]);
            reinterpret_cast<float2*>(Trow)[4] = make_float2(e[8], e[9]);
        }
        __syncthreads();                         // (1) T visible

        // colsum -> q
        if (cvalid) {
            const float* colp = &s_T[ck][cn][0][ct];
            float s0 = 0.f;
            #pragma unroll
            for (int m = 0; m < MM; m++) s0 += colp[m * RS];
            qa = s0;
            s_q[ck][cn][ct] = s0;
        }
        __syncthreads();                         // (2) q visible
        if (it == NITER) break;

        // cc (cvalid threads)
        if (cvalid) {
            const float4* qp4 = reinterpret_cast<const float4*>(&s_q[ck][cn][0]);
            float4 qx = qp4[0], qy = qp4[1];
            float2 qz = reinterpret_cast<const float2*>(qp4)[4];
            const float4* cr = reinterpret_cast<const float4*>(&s_C2sq[ck][ct][0]);
            float4 ca = cr[0], cb = cr[1];
            float2 c2 = reinterpret_cast<const float2*>(cr)[4];
            float cc = qx.x * ca.x + qx.y * ca.y + qx.z * ca.z + qx.w * ca.w
                     + qy.x * cb.x + qy.y * cb.y + qy.z * cb.z + qy.w * cb.w
                     + qz.x * c2.x + qz.y * c2.y;
            s_cc[ck][cn][ct] = cc;
        }

        // row work: q read, Y1, y2 matvec, partial update (pre-ccr)
        float q[MT];
        {
            const float4* qp4 = reinterpret_cast<const float4*>(&s_q[kh][gR][0]);
            float4 qx = qp4[0], qy = qp4[1];
            float2 qz = reinterpret_cast<const float2*>(qp4)[4];
            q[0] = qx.x; q[1] = qx.y; q[2] = qx.z; q[3] = qx.w;
            q[4] = qy.x; q[5] = qy.y; q[6] = qy.z; q[7] = qy.w;
            q[8] = qz.x; q[9] = qz.y;
        }
        float y1[MT];
        #pragma unroll
        for (int t = 0; t < MT; t++) y1[t] = cmpl ? q[t] : 0.f;
        unsigned mm = lmask;
        while (mm) {
            int b = __ffs(mm) - 1;
            mm &= mm - 1;
            const float4* rb4 = reinterpret_cast<const float4*>(&s_T[kh][gR][b][0]);
            float4 ra = rb4[0], rb = rb4[1];
            float2 rc = reinterpret_cast<const float2*>(rb4)[4];
            y1[0] += sgn * ra.x; y1[1] += sgn * ra.y; y1[2] += sgn * ra.z; y1[3] += sgn * ra.w;
            y1[4] += sgn * rb.x; y1[5] += sgn * rb.y; y1[6] += sgn * rb.z; y1[7] += sgn * rb.w;
            y1[8] += sgn * rc.x; y1[9] += sgn * rc.y;
        }
        #pragma unroll
        for (int s = 0; s < MT; s++) {
            float y2 = 0.f;
            #pragma unroll
            for (int t = 0; t < MT; t++) y2 = fmaf(y1[t], c2p[s * MT + t], y2);
            lt[s] += tgl * y2 - Mc[s];           // ccr applied after barrier
        }
        __syncthreads();                         // (3) cc visible

        {
            const float4* cp = reinterpret_cast<const float4*>(&s_cc[kh][gR][0]);
            float4 ca = cp[0], cb = cp[1];
            float2 c2 = reinterpret_cast<const float2*>(cp)[4];
            lt[0] -= ca.x; lt[1] -= ca.y; lt[2] -= ca.z; lt[3] -= ca.w;
            lt[4] -= cb.x; lt[5] -= cb.y; lt[6] -= cb.z; lt[7] -= cb.w;
            lt[8] -= c2.x; lt[9] -= c2.y;
        }
    }

    if (cvalid) {
        int nOut = nb + cn;
        if (nOut < NN)
            out[(size_t)nOut * (NTPL * MT) + (kb + ck) * MT + ct] = qa;
    }
}

extern "C" void kernel_launch(void* const* d_in, const int* in_sizes, int n_in,
                              void* d_out, int out_size, void* d_ws, size_t ws_size,
                              hipStream_t stream) {
    const float* x      = (const float*)d_in[0];
    const int*   eidx   = (const int*)d_in[1];
    const float* tmpl   = (const float*)d_in[2];
    const float* tmplf  = (const float*)d_in[3];
    const float* alpha0 = (const float*)d_in[4];
    float*       outp   = (float*)d_out;

    const int* dst = eidx + NN * DEG;
    float* G = (float*)d_ws;
    const size_t gbytes = (size_t)NN * NTPL * MT * sizeof(float);
    int useG = (ws_size >= gbytes) ? 1 : 0;

    if (useG)
        gcost_kernel<<<dim3(NN / GNV, 10), dim3(256), 0, stream>>>(x, tmplf, alpha0, G);

    srfgw_kernel<<<dim3((NN + NPB - 1) / NPB, NTPL / KPB), dim3(BS), 0, stream>>>(
        x, dst, tmpl, tmplf, alpha0, G, useG, outp);
}

// Round 17
// 203.921 us; speedup vs baseline: 1.1482x; 1.1482x over previous
//
#include <hip/hip_runtime.h>

// LTFGW semi-relaxed FGW — round 17: REVERT to round 14 (best: 203.6 us).
// Rounds 15/16 completed the occupancy/register bracket:
//   r15 (cap 4 w/EU): VGPR 52, Occ 41%, VALU work 112us -> srfgw 159 (slower)
//   r13/14 (default): VGPR 36, Occ 59%, VALU work 112us -> srfgw 141.5 (BEST)
//   r16 (8 w/EU,256): VGPR 32, Occ 77%, VALU work 163us -> srfgw 173.7 (slower
//     — 32-VGPR squeeze on a >=53-float live set triggers remat/AGPR cycling,
//     + doubled per-block preamble redundancy)
// All structural levers explored: packing 93% (kept), q via LDS colsum (kept),
// iter-0 fold (kept), native exp2/rcp log2-domain (kept), scalar-C2 matvec
// (kept); DS->VALU trade, waves cap, small blocks: all regressed. gcost v5 is
// ~at its L2 traffic floor; remaining ~40us gap is fixed dispatch overhead.

#define NN    6000
#define DEG   16
#define MM    17
#define NTPL  16
#define MT    10
#define NF    128
#define NITER 10
#define KPB   4
#define NPB   7
#define BS    512
#define RS    12            // padded T row stride (floats)
#define LOG2E 1.44269504088896340736f

template<int C>
__device__ __forceinline__ float ror_add(float v) {
    int s = __builtin_amdgcn_update_dpp(0, __float_as_int(v), C, 0xf, 0xf, true);
    return v + __int_as_float(s);
}

__device__ __forceinline__ float fexp2(float x) { return __builtin_amdgcn_exp2f(x); }
__device__ __forceinline__ float frcp(float x)  { return __builtin_amdgcn_rcpf(x); }

// sum over each 16-lane row (all lanes get the sum) — pure VALU DPP
__device__ __forceinline__ float reduce16(float v) {
    v = ror_add<0x121>(v);
    v = ror_add<0x122>(v);
    v = ror_add<0x124>(v);
    v = ror_add<0x128>(v);
    return v;
}

// ---------------- gcost v5 (round-14 verbatim)
#define GNV 40
__global__ __launch_bounds__(256) void gcost_kernel(
    const float* __restrict__ x, const float* __restrict__ F2g,
    const float* __restrict__ alpha0, float* __restrict__ G)
{
    const int kt  = blockIdx.y * 16 + (threadIdx.x >> 4);   // grid.y=10 -> 0..159
    const int l16 = threadIdx.x & 15;

    const float4* f2p = reinterpret_cast<const float4*>(F2g + (size_t)kt * NF) + l16 * 2;
    const float4 f2a = f2p[0], f2b = f2p[1];
    float sq = reduce16(f2a.x * f2a.x + f2a.y * f2a.y + f2a.z * f2a.z + f2a.w * f2a.w
                      + f2b.x * f2b.x + f2b.y * f2b.y + f2b.z * f2b.z + f2b.w * f2b.w);

    const float alpha  = 1.f / (1.f + __expf(-alpha0[0]));
    const float mcoefl = (1.f - alpha) * 10.f * LOG2E;
    const float base   = mcoefl * sq;
    const float m2     = -2.f * mcoefl;

    const int v0 = blockIdx.x * GNV;
    #pragma unroll 4
    for (int i = 0; i < GNV; i++) {
        const int v = v0 + i;
        const float4* xp = reinterpret_cast<const float4*>(x + (size_t)v * NF) + l16 * 2;
        float4 xa = xp[0], xb = xp[1];
        float d = xa.x * f2a.x + xa.y * f2a.y + xa.z * f2a.z + xa.w * f2a.w
                + xb.x * f2b.x + xb.y * f2b.y + xb.z * f2b.z + xb.w * f2b.w;
        d = reduce16(d);
        if (l16 == 0)
            G[(size_t)v * (NTPL * MT) + kt] = fmaf(m2, d, base);
    }
}

// ---------------- main kernel (round-13/14 verbatim)
__global__ __launch_bounds__(BS, 4) void srfgw_kernel(
    const float* __restrict__ x,
    const int*   __restrict__ dst,
    const float* __restrict__ C2g,
    const float* __restrict__ F2g,
    const float* __restrict__ alpha0,
    const float* __restrict__ G,
    int useG,
    float*       __restrict__ out)
{
    const int nb  = blockIdx.x * NPB;
    const int kb  = blockIdx.y * KPB;
    const int tid = threadIdx.x;

    __shared__ __align__(16) float s_T[KPB][NPB][MM][RS];     // 22848 B
    __shared__ __align__(16) float s_C2sq[KPB][MT][RS];       // 1920 B
    __shared__ __align__(16) float s_q[KPB][NPB][RS];         // 1344 B
    __shared__ __align__(16) float s_cc[KPB][NPB][RS];        // 1344 B
    __shared__ __align__(16) float s_A[KPB][RS];              // 192 B
    __shared__ __align__(16) float s_B[KPB][RS];              // 192 B
    __shared__ __align__(16) int   s_adj[NPB * MM][DEG];      // 7616 B
    __shared__ int      s_nbr[NPB][MM];
    __shared__ unsigned s_mask[NPB][MM];

    const float aval  = alpha0[0];
    const float alpha = 1.f / (1.f + __expf(-aval));
    const float gcoef = 2.f * alpha * 10.f;
    const float tgl   = 2.f * gcoef * LOG2E;
    const float gl2   = gcoef * LOG2E;

    // nbr (119 <= BS); node clamp: 7 does not divide 6000
    if (tid < NPB * MM) {
        int node = tid / MM, a0 = tid - node * MM;
        int nd  = nb + node;
        int ndc = nd < NN ? nd : NN - 1;
        s_nbr[node][a0]  = (a0 == 0) ? ndc : dst[(size_t)ndc * DEG + a0 - 1];
        s_mask[node][a0] = 0u;
    }
    __syncthreads();

    // adjacency rows (1904 > BS -> strided)
    for (int i = tid; i < NPB * MM * DEG; i += BS) {
        int r = i >> 4, j = i & 15;
        int node = r / MM, a0 = r - node * MM;
        s_adj[r][j] = dst[(size_t)s_nbr[node][a0] * DEG + j];
    }
    // C2sq (strided; kb offset)
    for (int i = tid; i < KPB * MT * MT; i += BS) {
        int kk = i / (MT * MT), rr = i - kk * (MT * MT);
        int rs = rr / MT, rt = rr - rs * MT;
        float v = C2g[(size_t)kb * MT * MT + i];
        s_C2sq[kk][rs][rt] = gl2 * v * v;
    }
    // iter-0 fold constants (40 <= BS)
    if (tid < KPB * MT) {
        int kk = tid / MT, s = tid - kk * MT;
        const float* cr = C2g + (size_t)(kb + kk) * MT * MT + s * MT;
        float rs = 0.f, rq = 0.f;
        #pragma unroll
        for (int t = 0; t < MT; t++) { float c = cr[t]; rs += c; rq = fmaf(c, c, rq); }
        s_A[kk][s] = (tgl / 170.f) * rs;
        s_B[kk][s] = 0.1f * gl2 * rq;
    }
    __syncthreads();

    // masks (2023 > BS -> strided), dual atomicOr symmetrization
    for (int i = tid; i < NPB * MM * MM; i += BS) {
        int node = i / (MM * MM), rr = i - node * (MM * MM);
        int pa = rr / MM, pb = rr - pa * MM;
        int vtgt = s_nbr[node][pb];
        const int* ar = s_adj[node * MM + pa];
        bool e = false;
        #pragma unroll
        for (int j = 0; j < DEG; j++) e = e | (ar[j] == vtgt);
        if (e) {
            atomicOr(&s_mask[node][pa], 1u << pb);
            atomicOr(&s_mask[node][pb], 1u << pa);
        }
    }
    __syncthreads();

    // ---- row mapping: kh wave-uniform; 119 rows flat-packed in 128 lanes ----
    const int  kh     = tid >> 7;              // 0..3
    const int  L      = tid & 127;
    const bool rvalid = L < NPB * MM;          // 119
    int gR = L / MM;
    int aR = L - gR * MM;
    if (!rvalid) { gR = 0; aR = 0; }

    const int k_u = __builtin_amdgcn_readfirstlane(kb + kh);
    const float* __restrict__ c2p = C2g + (size_t)k_u * MT * MT;

    const int vv = s_nbr[gR][aR];

    float Mc[MT];
    if (useG) {
        const float2* gp = reinterpret_cast<const float2*>(G + (size_t)vv * (NTPL * MT) + k_u * MT);
        #pragma unroll
        for (int j = 0; j < 5; j++) {
            float2 w = gp[j];
            Mc[2 * j] = w.x; Mc[2 * j + 1] = w.y;
        }
    } else {
        float dot[MT], sq2[MT];
        #pragma unroll
        for (int t = 0; t < MT; t++) { dot[t] = 0.f; sq2[t] = 0.f; }
        const float4* xr = reinterpret_cast<const float4*>(x + (size_t)vv * NF);
        const float4* fr = reinterpret_cast<const float4*>(F2g + (size_t)k_u * MT * NF);
        for (int f = 0; f < NF / 4; f++) {
            float4 xa = xr[f];
            #pragma unroll
            for (int t = 0; t < MT; t++) {
                float4 b = fr[t * (NF / 4) + f];
                dot[t] += xa.x * b.x + xa.y * b.y + xa.z * b.z + xa.w * b.w;
                sq2[t] += b.x * b.x + b.y * b.y + b.z * b.z + b.w * b.w;
            }
        }
        const float mcoefl = (1.f - alpha) * 10.f * LOG2E;
        #pragma unroll
        for (int t = 0; t < MT; t++) Mc[t] = mcoefl * (sq2[t] - 2.f * dot[t]);
    }

    unsigned mask = rvalid ? s_mask[gR][aR] : 0u;
    const int  pcnt = __popc(mask);
    const bool cmpl = pcnt > 8;
    unsigned   lmask = cmpl ? (~mask & 0x1FFFFu) : mask;
    if (!rvalid) lmask = 0u;
    const float sgn = cmpl ? -1.f : 1.f;
    const float P   = 1.f / 17.f;

    // ---- iter-0 analytic fold ----
    float lt[MT];
    {
        const float pcf = (float)pcnt;
        const float2* Ap = reinterpret_cast<const float2*>(&s_A[kh][0]);
        const float2* Bp = reinterpret_cast<const float2*>(&s_B[kh][0]);
        #pragma unroll
        for (int j = 0; j < 5; j++) {
            float2 av = Ap[j], bv = Bp[j];
            lt[2 * j]     = fmaf(pcf, av.x, -bv.x - Mc[2 * j]);
            lt[2 * j + 1] = fmaf(pcf, av.y, -bv.y - Mc[2 * j + 1]);
        }
    }

    // ---- colsum/cc mapping: tid < 280 -> (ck, cn, ct) ----
    const bool cvalid = tid < KPB * NPB * MT;  // 280
    int ck = 0, cn = 0, ct = 0;
    if (cvalid) {
        ck = tid / (NPB * MT);
        int rem = tid - ck * (NPB * MT);
        cn = rem / MT;
        ct = rem - cn * MT;
    }
    float qa = 0.f;

    float4* Trow = reinterpret_cast<float4*>(&s_T[kh][gR][aR][0]);

    for (int it = 1; it <= NITER; it++) {
        // thread-local softmax (log2 domain)
        float mx = lt[0];
        #pragma unroll
        for (int t = 1; t < MT; t++) mx = fmaxf(mx, lt[t]);
        float e[MT], ss = 0.f;
        #pragma unroll
        for (int t = 0; t < MT; t++) { e[t] = fexp2(lt[t] - mx); ss += e[t]; }
        float sc = P * frcp(ss);
        #pragma unroll
        for (int t = 0; t < MT; t++) e[t] *= sc;

        if (rvalid) {
            Trow[0] = make_float4(e[0], e[1], e[2], e[3]);
            Trow[1] = make_float4(e[4], e[5], e[6], e[7]);
            reinterpret_cast<float2*>(Trow)[4] = make_float2(e[8], e[9]);
        }
        __syncthreads();                         // (1) T visible

        // colsum -> q
        if (cvalid) {
            const float* colp = &s_T[ck][cn][0][ct];
            float s0 = 0.f;
            #pragma unroll
            for (int m = 0; m < MM; m++) s0 += colp[m * RS];
            qa = s0;
            s_q[ck][cn][ct] = s0;
        }
        __syncthreads();                         // (2) q visible
        if (it == NITER) break;

        // cc (cvalid threads)
        if (cvalid) {
            const float4* qp4 = reinterpret_cast<const float4*>(&s_q[ck][cn][0]);
            float4 qx = qp4[0], qy = qp4[1];
            float2 qz = reinterpret_cast<const float2*>(qp4)[4];
            const float4* cr = reinterpret_cast<const float4*>(&s_C2sq[ck][ct][0]);
            float4 ca = cr[0], cb = cr[1];
            float2 c2 = reinterpret_cast<const float2*>(cr)[4];
            float cc = qx.x * ca.x + qx.y * ca.y + qx.z * ca.z + qx.w * ca.w
                     + qy.x * cb.x + qy.y * cb.y + qy.z * cb.z + qy.w * cb.w
                     + qz.x * c2.x + qz.y * c2.y;
            s_cc[ck][cn][ct] = cc;
        }

        // row work: q read, Y1, y2 matvec, partial update (pre-ccr)
        float q[MT];
        {
            const float4* qp4 = reinterpret_cast<const float4*>(&s_q[kh][gR][0]);
            float4 qx = qp4[0], qy = qp4[1];
            float2 qz = reinterpret_cast<const float2*>(qp4)[4];
            q[0] = qx.x; q[1] = qx.y; q[2] = qx.z; q[3] = qx.w;
            q[4] = qy.x; q[5] = qy.y; q[6] = qy.z; q[7] = qy.w;
            q[8] = qz.x; q[9] = qz.y;
        }
        float y1[MT];
        #pragma unroll
        for (int t = 0; t < MT; t++) y1[t] = cmpl ? q[t] : 0.f;
        unsigned mm = lmask;
        while (mm) {
            int b = __ffs(mm) - 1;
            mm &= mm - 1;
            const float4* rb4 = reinterpret_cast<const float4*>(&s_T[kh][gR][b][0]);
            float4 ra = rb4[0], rb = rb4[1];
            float2 rc = reinterpret_cast<const float2*>(rb4)[4];
            y1[0] += sgn * ra.x; y1[1] += sgn * ra.y; y1[2] += sgn * ra.z; y1[3] += sgn * ra.w;
            y1[4] += sgn * rb.x; y1[5] += sgn * rb.y; y1[6] += sgn * rb.z; y1[7] += sgn * rb.w;
            y1[8] += sgn * rc.x; y1[9] += sgn * rc.y;
        }
        #pragma unroll
        for (int s = 0; s < MT; s++) {
            float y2 = 0.f;
            #pragma unroll
            for (int t = 0; t < MT; t++) y2 = fmaf(y1[t], c2p[s * MT + t], y2);
            lt[s] += tgl * y2 - Mc[s];           // ccr applied after barrier
        }
        __syncthreads();                         // (3) cc visible

        {
            const float4* cp = reinterpret_cast<const float4*>(&s_cc[kh][gR][0]);
            float4 ca = cp[0], cb = cp[1];
            float2 c2 = reinterpret_cast<const float2*>(cp)[4];
            lt[0] -= ca.x; lt[1] -= ca.y; lt[2] -= ca.z; lt[3] -= ca.w;
            lt[4] -= cb.x; lt[5] -= cb.y; lt[6] -= cb.z; lt[7] -= cb.w;
            lt[8] -= c2.x; lt[9] -= c2.y;
        }
    }

    if (cvalid) {
        int nOut = nb + cn;
        if (nOut < NN)
            out[(size_t)nOut * (NTPL * MT) + (kb + ck) * MT + ct] = qa;
    }
}

extern "C" void kernel_launch(void* const* d_in, const int* in_sizes, int n_in,
                              void* d_out, int out_size, void* d_ws, size_t ws_size,
                              hipStream_t stream) {
    const float* x      = (const float*)d_in[0];
    const int*   eidx   = (const int*)d_in[1];
    const float* tmpl   = (const float*)d_in[2];
    const float* tmplf  = (const float*)d_in[3];
    const float* alpha0 = (const float*)d_in[4];
    float*       outp   = (float*)d_out;

    const int* dst = eidx + NN * DEG;
    float* G = (float*)d_ws;
    const size_t gbytes = (size_t)NN * NTPL * MT * sizeof(float);
    int useG = (ws_size >= gbytes) ? 1 : 0;

    if (useG)
        gcost_kernel<<<dim3(NN / GNV, 10), dim3(256), 0, stream>>>(x, tmplf, alpha0, G);

    srfgw_kernel<<<dim3((NN + NPB - 1) / NPB, NTPL / KPB), dim3(BS), 0, stream>>>(
        x, dst, tmpl, tmplf, alpha0, G, useG, outp);
}